// Round 5
// baseline (11289.325 us; speedup 1.0000x reference)
//
#include <hip/hip_runtime.h>
#include <stdint.h>

#define T_STEPS 2048
#define HID 1024
#define G4 4096
#define NWG 64

typedef __attribute__((ext_vector_type(8))) short short8;
typedef __attribute__((ext_vector_type(4))) float float4v;
typedef __attribute__((ext_vector_type(4))) unsigned int uint4v;
typedef unsigned long long ull;

// ---------- ws layout ----------
// [0, 262144)              : h double buffer, TAGGED: 2 x 128KB,
//                            ull[parity][wg][batch][ck] = {u32 pk, u32 tag}
//                            pk = bf16 cols (2ck, 2ck+1) of batch; tag = step
//                            of the h snapshot (h(t) carries tag t).
// [262144, 262148)         : dtype flag (1 = bf16 inputs, 0 = fp32 inputs)
// [266240, 397312)         : c state fp32 [32][1024] (persists across chunks)
// [0x100000, +TC*262144)   : x_proj bf16 chunk, [t_local][g][b]
#define HBUF_OFF 0ull
#define DT_OFF   262144ull
#define CST_OFF  266240ull
#define XP_OFF   0x100000ull

__device__ inline unsigned short f2bf(float f) {
  union { float f; unsigned int u; } v; v.f = f;
  unsigned int u = v.u;
  return (unsigned short)((u + 0x7fffu + ((u >> 16) & 1u)) >> 16);
}
__device__ inline float bf2f(unsigned short h) {
  union { unsigned int u; float f; } v; v.u = ((unsigned int)h) << 16;
  return v.f;
}
__device__ inline short8 pack8(float4 a, float4 b) {
  short8 r;
  r[0] = (short)f2bf(a.x); r[1] = (short)f2bf(a.y);
  r[2] = (short)f2bf(a.z); r[3] = (short)f2bf(a.w);
  r[4] = (short)f2bf(b.x); r[5] = (short)f2bf(b.y);
  r[6] = (short)f2bf(b.z); r[7] = (short)f2bf(b.w);
  return r;
}

// =====================================================================
// Dtype sniffer (unchanged)
// =====================================================================
__global__ void dtype_sniff(const unsigned short* __restrict__ w,
                            unsigned int* __restrict__ dt) {
  __shared__ int red[256];
  const int tid = threadIdx.x;
  int cnt = 0;
#pragma unroll
  for (int i = 0; i < 4; i++) {
    unsigned short h = w[tid * 4 + i];
    unsigned e = (h >> 7) & 0xFF;
    if (h == 0 || (e >= 100 && e <= 123)) cnt++;
  }
  red[tid] = cnt;
  __syncthreads();
  for (int s = 128; s > 0; s >>= 1) {
    if (tid < s) red[tid] += red[tid + s];
    __syncthreads();
  }
  if (tid == 0) dt[0] = (red[0] >= 922) ? 1u : 0u;   // 90% of 1024
}

// =====================================================================
// Phase A (unchanged): x_proj[tl][g][b] = x[b][t0+tl][:] . W_ih[g][:] + bias
// =====================================================================
__global__ __launch_bounds__(256) void xproj_gemm(
    const void* __restrict__ x, const void* __restrict__ Wih,
    const void* __restrict__ bih, const void* __restrict__ bhh,
    unsigned short* __restrict__ xp, int t0,
    const unsigned int* __restrict__ dt)
{
  __shared__ char smem[32768];
  __shared__ float bias_s[128];
  unsigned short* As = (unsigned short*)smem;            // [128][40]
  unsigned short* Bs = (unsigned short*)(smem + 10240);

  const bool isbf = (*dt != 0);

  const int bid = blockIdx.x;
  const int panel = bid >> 9;
  const int within = bid & 511;
  const int nt = within & 31;
  const int mt = (panel << 4) + (within >> 5);
  const int m0 = mt * 128;
  const int n0 = nt * 128;
  const int tl0 = m0 >> 5;

  const int tid = threadIdx.x;
  if (tid < 128) {
    bias_s[tid] = isbf
        ? bf2f(((const unsigned short*)bih)[n0 + tid]) +
          bf2f(((const unsigned short*)bhh)[n0 + tid])
        : ((const float*)bih)[n0 + tid] + ((const float*)bhh)[n0 + tid];
  }

  const int w = tid >> 6, lane = tid & 63;
  const int quad = lane >> 4, lr = lane & 15;
  const int wm = (w & 1) * 64, wn = (w >> 1) * 64;

  float4v acc[4][4];
#pragma unroll
  for (int i = 0; i < 4; i++)
#pragma unroll
    for (int j = 0; j < 4; j++) acc[i][j] = (float4v){0.f, 0.f, 0.f, 0.f};

  const int r = tid >> 1, half = tid & 1;
  const size_t aoff =
      ((size_t)(r & 31) * T_STEPS + (size_t)(t0 + tl0 + (r >> 5))) * HID + half * 16;
  const size_t boff = (size_t)(n0 + r) * HID + half * 16;
  unsigned short* adst = As + r * 40 + half * 16;
  unsigned short* bdst = Bs + r * 40 + half * 16;

  for (int k0 = 0; k0 < HID; k0 += 32) {
    __syncthreads();
    if (isbf) {
      const unsigned short* a16 = (const unsigned short*)x + aoff + k0;
      const unsigned short* b16 = (const unsigned short*)Wih + boff + k0;
      *(short8*)(adst)     = *(const short8*)(a16);
      *(short8*)(adst + 8) = *(const short8*)(a16 + 8);
      *(short8*)(bdst)     = *(const short8*)(b16);
      *(short8*)(bdst + 8) = *(const short8*)(b16 + 8);
    } else {
      const float4* af = (const float4*)((const float*)x + aoff + k0);
      const float4* bf = (const float4*)((const float*)Wih + boff + k0);
      float4 a0 = af[0], a1 = af[1], a2 = af[2], a3 = af[3];
      float4 b0 = bf[0], b1 = bf[1], b2 = bf[2], b3 = bf[3];
      *(short8*)(adst)     = pack8(a0, a1);
      *(short8*)(adst + 8) = pack8(a2, a3);
      *(short8*)(bdst)     = pack8(b0, b1);
      *(short8*)(bdst + 8) = pack8(b2, b3);
    }
    __syncthreads();
    short8 afr[4], bfr[4];
#pragma unroll
    for (int i = 0; i < 4; i++)
      afr[i] = *(const short8*)(As + (wm + i * 16 + lr) * 40 + quad * 8);
#pragma unroll
    for (int j = 0; j < 4; j++)
      bfr[j] = *(const short8*)(Bs + (wn + j * 16 + lr) * 40 + quad * 8);
#pragma unroll
    for (int i = 0; i < 4; i++)
#pragma unroll
      for (int j = 0; j < 4; j++)
        acc[i][j] = __builtin_amdgcn_mfma_f32_16x16x32_bf16(afr[i], bfr[j], acc[i][j], 0, 0, 0);
  }

  __syncthreads();
  unsigned short* ep = (unsigned short*)smem;
#pragma unroll
  for (int i = 0; i < 4; i++)
#pragma unroll
    for (int j = 0; j < 4; j++)
#pragma unroll
      for (int rr = 0; rr < 4; rr++) {
        int ml = wm + i * 16 + quad * 4 + rr;
        int nl = wn + j * 16 + lr;
        float v = acc[i][j][rr] + bias_s[nl];
        ep[(((ml >> 5) * 128) + nl) * 32 + (ml & 31)] = f2bf(v);
      }
  __syncthreads();
#pragma unroll
  for (int tl = 0; tl < 4; tl++) {
    const uint4* s4 = (const uint4*)(smem + tl * 8192);
    uint4* d4 = (uint4*)(xp + ((size_t)(tl0 + tl) * G4 + n0) * 32);
    for (int i = tid; i < 512; i += 256) d4[i] = s4[i];
  }
}

// =====================================================================
// Phase R: persistent LSTM recurrence. 64 WGs x 4 waves, K-split as r4,
// but with FUSED flag+data publish: each thread's h-pair is stored as one
// 8B atomic {pk, step-tag}. The consumer's gather IS the synchronization:
// 32 in-flight dwordx4 loads return {pk,tag,pk,tag}; min-reduce the 64
// tags; retry all 32 loads until every tag == t. Removes publish-drain,
// flag store, and the separate poll round trip from the critical path.
//
// Safety arguments:
//  - 8B aligned stores commit atomically -> a matching tag implies the
//    co-located pk is from the same step (no torn reads within 8B).
//  - tags in parity buffer (t&1) are always <= t: a producer reaches
//    publish(t+2) only after gathering h(t+1), which requires ALL WGs to
//    have published h(t+1), which requires this WG to have consumed h(t)
//    -- contradiction while it is still gathering h(t).
//  - overwrite safety: WG publishes h(t+1) (parity (t+1)&1, overwriting
//    h(t-1)) only after its barrier, i.e. after its 4 waves saw tag==t
//    from all 64 producers; producer's tag==t implies it passed its own
//    barrier for step t-1, i.e. finished reading h(t-1).
// gpart is parity-double-buffered -> single barrier per step.
// =====================================================================
__global__ __launch_bounds__(256, 1) void lstm_rec(
    const void* __restrict__ Whh,
    const unsigned short* __restrict__ xp,
    ull* __restrict__ hbuf,              // 2 x 16384 ull {pk, tag}
    float* __restrict__ cstate,          // [32][1024] fp32, persists
    void* __restrict__ out,              // [h(32x1024) ; c(32x1024)]
    int t0, int tc,
    const unsigned int* __restrict__ dt)
{
  __shared__ float gpart[2][4][64][36];  // [parity][wave][gate*16+col][batch]

  const bool isbf = (*dt != 0);
  const int wg = blockIdx.x;
  const int tid = threadIdx.x;
  const int w = tid >> 6, lane = tid & 63;
  const int quad = lane >> 4, lr = lane & 15;

  // --- W_hh B-fragments: wave w = K-quarter [256w,+256), all 4 gates ---
  short8 bfrag[32];
#pragma unroll
  for (int q = 0; q < 4; q++) {
    const size_t grow = (size_t)q * HID + wg * 16 + lr;
    if (isbf) {
      const unsigned short* wrow = (const unsigned short*)Whh + grow * HID;
#pragma unroll
      for (int s = 0; s < 8; s++)
        bfrag[q * 8 + s] = *(const short8*)(wrow + w * 256 + s * 32 + quad * 8);
    } else {
      const float* wrow = (const float*)Whh + grow * HID;
#pragma unroll
      for (int s = 0; s < 8; s++) {
        float4 f0 = *(const float4*)(wrow + w * 256 + s * 32 + quad * 8);
        float4 f1 = *(const float4*)(wrow + w * 256 + s * 32 + quad * 8 + 4);
        bfrag[q * 8 + s] = pack8(f0, f1);
      }
    }
  }

  // cell ownership: (batch cb, local h-cols j0, j1)
  const int cb = 8 * w + (lane >> 3);
  const int ck = lane & 7;
  const int j0 = 2 * ck, j1 = j0 + 1;
  const int gc0 = wg * 16 + j0, gc1 = gc0 + 1;
  float cs0 = cstate[(size_t)cb * HID + gc0];
  float cs1 = cstate[(size_t)cb * HID + gc1];
  long budget = 200000000;

  // gather base (bytes within one 128KB parity buffer):
  // byte(s,m,chunk) = (16w + 2s + (quad>>1))*2048 + (m*16+lr)*64
  //                   + (quad&1)*32 + chunk*16
  const int goff = (16 * w + (quad >> 1)) * 2048 + lr * 64 + (quad & 1) * 32;

  for (int t = t0; t < t0 + tc; t++) {
    // ---- prefetch xp gate values (cached loads, issued early) ----
    const unsigned short* xpt = xp + (size_t)(t - t0) * (G4 * 32);
    unsigned short rx0 = xpt[(size_t)gc0 * 32 + cb];
    unsigned short rx1 = xpt[(size_t)(HID + gc0) * 32 + cb];
    unsigned short rx2 = xpt[(size_t)(2 * HID + gc0) * 32 + cb];
    unsigned short rx3 = xpt[(size_t)(3 * HID + gc0) * 32 + cb];
    unsigned short rx4 = xpt[(size_t)gc1 * 32 + cb];
    unsigned short rx5 = xpt[(size_t)(HID + gc1) * 32 + cb];
    unsigned short rx6 = xpt[(size_t)(2 * HID + gc1) * 32 + cb];
    unsigned short rx7 = xpt[(size_t)(3 * HID + gc1) * 32 + cb];

    // ---- fused gather + validate: 32 x dwordx4 {pk,tag,pk,tag} ----
    uint4v lb[32];
    {
      const char* gb = (const char*)hbuf + (size_t)(t & 1) * 131072 + goff;
      const unsigned tagt = (unsigned)t;
      for (;;) {
#pragma unroll
        for (int s = 0; s < 8; s++) {
          const char* p = gb + s * 4096;
          asm volatile(
              "global_load_dwordx4 %0, %4, off sc0 sc1\n\t"
              "global_load_dwordx4 %1, %4, off offset:16 sc0 sc1\n\t"
              "global_load_dwordx4 %2, %4, off offset:1024 sc0 sc1\n\t"
              "global_load_dwordx4 %3, %4, off offset:1040 sc0 sc1"
              : "=v"(lb[4 * s]), "=v"(lb[4 * s + 1]),
                "=v"(lb[4 * s + 2]), "=v"(lb[4 * s + 3])
              : "v"(p) : "memory");
        }
        asm volatile("s_waitcnt vmcnt(0)" ::: "memory");
        __builtin_amdgcn_sched_barrier(0);
        unsigned mn = 0xFFFFFFFFu;
#pragma unroll
        for (int i = 0; i < 32; i++) {
          unsigned ta = lb[i][1], tb = lb[i][3];
          unsigned mi = ta < tb ? ta : tb;
          mn = mi < mn ? mi : mn;
        }
        if (__all(mn == tagt)) break;
        if (--budget < 0) break;
      }
    }

    // ---- in-register MFMA: 64 MFMAs, 8 independent acc chains ----
    float4v acc[2][4];
#pragma unroll
    for (int m = 0; m < 2; m++)
#pragma unroll
      for (int q = 0; q < 4; q++) acc[m][q] = (float4v){0.f, 0.f, 0.f, 0.f};
#pragma unroll
    for (int s = 0; s < 8; s++) {
      uint4v pa, pb;
      pa[0] = lb[4 * s][0];     pa[1] = lb[4 * s][2];
      pa[2] = lb[4 * s + 1][0]; pa[3] = lb[4 * s + 1][2];
      pb[0] = lb[4 * s + 2][0]; pb[1] = lb[4 * s + 2][2];
      pb[2] = lb[4 * s + 3][0]; pb[3] = lb[4 * s + 3][2];
      short8 a0 = *(short8*)&pa;
      short8 a1 = *(short8*)&pb;
#pragma unroll
      for (int q = 0; q < 4; q++) {
        acc[0][q] = __builtin_amdgcn_mfma_f32_16x16x32_bf16(a0, bfrag[q * 8 + s], acc[0][q], 0, 0, 0);
        acc[1][q] = __builtin_amdgcn_mfma_f32_16x16x32_bf16(a1, bfrag[q * 8 + s], acc[1][q], 0, 0, 0);
      }
    }

    // ---- cross-wave K reduction (parity-double-buffered, 1 barrier) ----
    const int pp = t & 1;
#pragma unroll
    for (int m = 0; m < 2; m++)
#pragma unroll
      for (int q = 0; q < 4; q++)
        *(float4v*)&gpart[pp][w][q * 16 + lr][m * 16 + quad * 4] = acc[m][q];
    __syncthreads();   // partials ready; also: all 4 waves finished their
                       // gathers -> all 64 WGs >= t -> publish is safe

    // ---- cell: sum 4 partials per gate + xp, then LSTM elementwise ----
    {
      float gi0 = bf2f(rx0), gf0 = bf2f(rx1), gg0 = bf2f(rx2), go0 = bf2f(rx3);
      float gi1 = bf2f(rx4), gf1 = bf2f(rx5), gg1 = bf2f(rx6), go1 = bf2f(rx7);
#pragma unroll
      for (int p = 0; p < 4; p++) {
        gi0 += gpart[pp][p][j0][cb];
        gf0 += gpart[pp][p][16 + j0][cb];
        gg0 += gpart[pp][p][32 + j0][cb];
        go0 += gpart[pp][p][48 + j0][cb];
        gi1 += gpart[pp][p][j1][cb];
        gf1 += gpart[pp][p][16 + j1][cb];
        gg1 += gpart[pp][p][32 + j1][cb];
        go1 += gpart[pp][p][48 + j1][cb];
      }
      float si0 = 1.f / (1.f + __expf(-gi0));
      float sf0 = 1.f / (1.f + __expf(-gf0));
      float tg0 = tanhf(gg0);
      float so0 = 1.f / (1.f + __expf(-go0));
      cs0 = sf0 * cs0 + si0 * tg0;
      float hn0 = so0 * tanhf(cs0);

      float si1 = 1.f / (1.f + __expf(-gi1));
      float sf1 = 1.f / (1.f + __expf(-gf1));
      float tg1 = tanhf(gg1);
      float so1 = 1.f / (1.f + __expf(-go1));
      cs1 = sf1 * cs1 + si1 * tg1;
      float hn1 = so1 * tanhf(cs1);

      // ---- publish {data, tag} as ONE 8B atomic store; no drain, no flag
      unsigned pk = (unsigned)f2bf(hn0) | ((unsigned)f2bf(hn1) << 16);
      ull pv = (ull)pk | ((ull)(unsigned)(t + 1) << 32);
      ull* dst = hbuf + (size_t)((t + 1) & 1) * 16384 + wg * 256 + cb * 8 + ck;
      __hip_atomic_store(dst, pv, __ATOMIC_RELAXED, __HIP_MEMORY_SCOPE_AGENT);

      if (t == T_STEPS - 1) {
        if (isbf) {
          unsigned short* ob = (unsigned short*)out;
          ob[(size_t)cb * HID + gc0] = f2bf(hn0);
          ob[(size_t)cb * HID + gc1] = f2bf(hn1);
          ob[32768 + (size_t)cb * HID + gc0] = f2bf(cs0);
          ob[32768 + (size_t)cb * HID + gc1] = f2bf(cs1);
        } else {
          float* of = (float*)out;
          of[(size_t)cb * HID + gc0] = hn0;
          of[(size_t)cb * HID + gc1] = hn1;
          of[32768 + (size_t)cb * HID + gc0] = cs0;
          of[32768 + (size_t)cb * HID + gc1] = cs1;
        }
      }
    }
  }

  // persist c for the next chunk
  cstate[(size_t)cb * HID + gc0] = cs0;
  cstate[(size_t)cb * HID + gc1] = cs1;
}

extern "C" void kernel_launch(void* const* d_in, const int* in_sizes, int n_in,
                              void* d_out, int out_size, void* d_ws, size_t ws_size,
                              hipStream_t stream) {
  (void)in_sizes; (void)n_in; (void)out_size;
  const void* x   = d_in[0];
  const void* Wih = d_in[1];
  const void* Whh = d_in[2];
  const void* bih = d_in[3];
  const void* bhh = d_in[4];

  char* ws = (char*)d_ws;
  ull*          hbuf   = (ull*)(ws + HBUF_OFF);
  unsigned int* dt     = (unsigned int*)(ws + DT_OFF);
  float*        cstate = (float*)(ws + CST_OFF);
  unsigned short* xp   = (unsigned short*)(ws + XP_OFF);

  int tc = 2048;
  while (tc > 16 && XP_OFF + (size_t)tc * 262144ull > ws_size) tc >>= 1;

  hipMemsetAsync(ws, 0, CST_OFF + 131072, stream);   // hbuf tags=0, cstate=0

  hipLaunchKernelGGL(dtype_sniff, dim3(1), dim3(256), 0, stream,
                     (const unsigned short*)Wih, dt);

  for (int t0 = 0; t0 < T_STEPS; t0 += tc) {
    hipLaunchKernelGGL(xproj_gemm, dim3(tc * 8), dim3(256), 0, stream,
                       x, Wih, bih, bhh, xp, t0, dt);
    hipLaunchKernelGGL(lstm_rec, dim3(NWG), dim3(256), 0, stream,
                       Whh, xp, hbuf, cstate, d_out, t0, tc, dt);
  }
}